// Round 4
// baseline (1810.807 us; speedup 1.0000x reference)
//
#include <hip/hip_runtime.h>
#include <cstdint>

#define N_NODES   10000
#define N_EDGES   640000
#define NODE_OUT  (N_NODES * 128)       // 1,280,000 node-output floats

typedef __bf16 bf16;
typedef bf16  bf16x8 __attribute__((ext_vector_type(8)));
typedef float f32x4  __attribute__((ext_vector_type(4)));

// transposed bf16 weight offsets inside ws ([N][K] row-major, elements)
#define EW1T_OFF 0        // 128 x 384
#define EW2T_OFF 49152    // 128 x 128
#define NW1T_OFF 65536    // 128 x 256
#define NW2T_OFF 98304    // 128 x 128

// -------- weight convert+transpose: fp32 W[K][N] -> bf16 WT[N][K] --------
__global__ void transpose_weights(const float* __restrict__ eW1, const float* __restrict__ eW2,
                                  const float* __restrict__ nW1, const float* __restrict__ nW2,
                                  bf16* __restrict__ wt) {
  int gid = blockIdx.x * 256 + threadIdx.x;   // 448*256 = 114688 exactly
  const float* src; bf16* dst; int K, off;
  if (gid < 49152)      { src = eW1; dst = wt + EW1T_OFF; K = 384; off = gid; }
  else if (gid < 65536) { src = eW2; dst = wt + EW2T_OFF; K = 128; off = gid - 49152; }
  else if (gid < 98304) { src = nW1; dst = wt + NW1T_OFF; K = 256; off = gid - 65536; }
  else                  { src = nW2; dst = wt + NW2T_OFF; K = 128; off = gid - 98304; }
  int k = off >> 7, n = off & 127;
  dst[n * K + k] = (bf16)src[off];
}

__device__ __forceinline__ float softplus_f(float v) {
  return v > 20.f ? v : __logf(1.f + __expf(v));
}

// load 8 consecutive fp32 and round to a bf16x8 fragment
__device__ __forceinline__ bf16x8 load_cvt8(const float* __restrict__ src) {
  float4 f0 = *(const float4*)src;
  float4 f1 = *(const float4*)(src + 4);
  bf16x8 h;
  h[0] = (bf16)f0.x; h[1] = (bf16)f0.y; h[2] = (bf16)f0.z; h[3] = (bf16)f0.w;
  h[4] = (bf16)f1.x; h[5] = (bf16)f1.y; h[6] = (bf16)f1.z; h[7] = (bf16)f1.w;
  return h;
}

// pack two f32 into one u32 of 2 bf16 (lo in low 16 bits)
__device__ __forceinline__ uint32_t pack2(float lo, float hi) {
  uint16_t a = __builtin_bit_cast(uint16_t, (bf16)lo);
  uint16_t b = __builtin_bit_cast(uint16_t, (bf16)hi);
  return ((uint32_t)b << 16) | (uint32_t)a;
}

// ===================== edge MLP (transposed, zero-barrier main loop) ==========
// 512 thr = 8 waves, 1 block/CU. Wave owns 32 edges (2 e-tiles of 16).
// G1^T: D1^T = eW1T(A, LDS frags) @ X(B, direct global).  acc: [8 n-tiles][2 e].
// C1 handoff via 4-lane shuffle transform -> A-frags for G2 (normal orientation).
// G2: D2 = C1(A) @ eW2(B, LDS frags) -> edge_out.
__global__ void __launch_bounds__(512, 2)
edge_mlp(const float* __restrict__ x, const int* __restrict__ eidx,
         const float* __restrict__ edge_attr,
         const float* __restrict__ eb1, const float* __restrict__ eb2,
         const bf16* __restrict__ wt, float* __restrict__ edge_out)
{
  extern __shared__ char smem[];
  bf16* w1f = (bf16*)smem;              // 96 frags (t*12+c) x 512 elem = 98,304 B
  bf16* w2f = (bf16*)(smem + 98304);    // 32 frags (t*4+c)  x 512 elem = 32,768 B

  const int tid  = threadIdx.x;
  const int wave = tid >> 6, lane = tid & 63;
  const int ln15 = lane & 15, lq = lane >> 4;

  // ---- one-time: stage weights into fragment-linear LDS (conflict-free reads) ----
  #pragma unroll
  for (int it = 0; it < 12; ++it) {
    int idx = it * 512 + tid;           // frag f = idx>>6, lane-in-frag l = idx&63
    int f = idx >> 6, l = idx & 63;
    int t = f / 12, c = f - t * 12;
    *(uint4*)&w1f[idx * 8] =
        *(const uint4*)&wt[EW1T_OFF + (t * 16 + (l & 15)) * 384 + c * 32 + (l >> 4) * 8];
  }
  #pragma unroll
  for (int it = 0; it < 4; ++it) {
    int idx = it * 512 + tid;
    int f = idx >> 6, l = idx & 63;
    int t = f >> 2, c = f & 3;
    *(uint4*)&w2f[idx * 8] =
        *(const uint4*)&wt[EW2T_OFF + (t * 16 + (l & 15)) * 128 + c * 32 + (l >> 4) * 8];
  }
  __syncthreads();                      // only barrier in the kernel

  // biases (constant across tiles): G1^T rows are n = t*16+lq*4+r; G2 cols n = t*16+ln15
  f32x4 b1v[8]; float b2s[8];
  #pragma unroll
  for (int t = 0; t < 8; ++t) {
    b1v[t] = *(const f32x4*)&eb1[t * 16 + lq * 4];
    b2s[t] = eb2[t * 16 + ln15];
  }

  const int srcA = ln15 + ((lq & 1) << 5);   // shuffle sources for C1 transform
  const int srcB = srcA + 16;
  const bool lql = (lq < 2);

  for (int tile = blockIdx.x * 8 + wave; tile < N_EDGES / 32; tile += gridDim.x * 8) {
    const int e0 = tile * 32;
    int rrow[2], rcol[2];
    #pragma unroll
    for (int e = 0; e < 2; ++e) {
      rrow[e] = eidx[e0 + e * 16 + ln15];
      rcol[e] = eidx[N_EDGES + e0 + e * 16 + ln15];
    }

    // ---- G1^T: 12 K-chunks, B direct from global ----
    f32x4 acc[8][2];
    #pragma unroll
    for (int t = 0; t < 8; ++t)
      #pragma unroll
      for (int e = 0; e < 2; ++e)
        acc[t][e] = f32x4{0.f, 0.f, 0.f, 0.f};

    #pragma unroll
    for (int c = 0; c < 12; ++c) {
      bf16x8 bf[2];
      #pragma unroll
      for (int e = 0; e < 2; ++e) {
        const float* src;
        if (c < 4)      src = x + (size_t)rrow[e] * 128 + c * 32 + lq * 8;
        else if (c < 8) src = x + (size_t)rcol[e] * 128 + (c - 4) * 32 + lq * 8;
        else            src = edge_attr + (size_t)(e0 + e * 16 + ln15) * 128 + (c - 8) * 32 + lq * 8;
        bf[e] = load_cvt8(src);
      }
      #pragma unroll
      for (int t = 0; t < 8; ++t) {
        bf16x8 af = *(const bf16x8*)&w1f[(t * 12 + c) * 512 + lane * 8];
        #pragma unroll
        for (int e = 0; e < 2; ++e)
          acc[t][e] = __builtin_amdgcn_mfma_f32_16x16x32_bf16(af, bf[e], acc[t][e], 0, 0, 0);
      }
    }

    // ---- softplus + bias, pack C1 to bf16 pairs ----
    uint32_t P[8][2][2];
    #pragma unroll
    for (int t = 0; t < 8; ++t)
      #pragma unroll
      for (int e = 0; e < 2; ++e) {
        float v0 = softplus_f(acc[t][e][0] + b1v[t][0]);
        float v1 = softplus_f(acc[t][e][1] + b1v[t][1]);
        float v2 = softplus_f(acc[t][e][2] + b1v[t][2]);
        float v3 = softplus_f(acc[t][e][3] + b1v[t][3]);
        P[t][e][0] = pack2(v0, v1);
        P[t][e][1] = pack2(v2, v3);
      }

    // ---- G2 (normal): A = shuffled C1, B = w2f; 4 K-chunks ----
    f32x4 a2[8][2];
    #pragma unroll
    for (int t = 0; t < 8; ++t)
      #pragma unroll
      for (int e = 0; e < 2; ++e)
        a2[t][e] = f32x4{0.f, 0.f, 0.f, 0.f};

    #pragma unroll
    for (int c = 0; c < 4; ++c) {
      bf16x8 F[2];
      #pragma unroll
      for (int e = 0; e < 2; ++e) {
        int p0lo = __shfl((int)P[2 * c][e][0], srcA);
        int p0hi = __shfl((int)P[2 * c][e][1], srcA);
        int p1lo = __shfl((int)P[2 * c + 1][e][0], srcA);
        int p1hi = __shfl((int)P[2 * c + 1][e][1], srcA);
        int q0lo = __shfl((int)P[2 * c][e][0], srcB);
        int q0hi = __shfl((int)P[2 * c][e][1], srcB);
        int q1lo = __shfl((int)P[2 * c + 1][e][0], srcB);
        int q1hi = __shfl((int)P[2 * c + 1][e][1], srcB);
        uint4 u;
        u.x = lql ? (uint32_t)p0lo : (uint32_t)p1lo;
        u.y = lql ? (uint32_t)p0hi : (uint32_t)p1hi;
        u.z = lql ? (uint32_t)q0lo : (uint32_t)q1lo;
        u.w = lql ? (uint32_t)q0hi : (uint32_t)q1hi;
        F[e] = __builtin_bit_cast(bf16x8, u);
      }
      #pragma unroll
      for (int t = 0; t < 8; ++t) {
        bf16x8 bw = *(const bf16x8*)&w2f[(t * 4 + c) * 512 + lane * 8];
        #pragma unroll
        for (int e = 0; e < 2; ++e)
          a2[t][e] = __builtin_amdgcn_mfma_f32_16x16x32_bf16(F[e], bw, a2[t][e], 0, 0, 0);
      }
    }

    // ---- store edge_out: row e = e0+e*16+lq*4+r, col n = t*16+ln15 ----
    #pragma unroll
    for (int t = 0; t < 8; ++t)
      #pragma unroll
      for (int e = 0; e < 2; ++e)
        #pragma unroll
        for (int r = 0; r < 4; ++r)
          edge_out[(size_t)(e0 + e * 16 + lq * 4 + r) * 128 + t * 16 + ln15] = a2[t][e][r] + b2s[t];
  }
}

// ===================== node MLP (same skeleton) ==============================
// G3^T: D3^T = nW1T(A, LDS) @ [x_row|C2](B, global).  Shuffle -> G4 normal -> scatter.
__global__ void __launch_bounds__(512, 2)
node_mlp(const float* __restrict__ x, const int* __restrict__ eidx,
         const float* __restrict__ edge_new,
         const float* __restrict__ nb1, const float* __restrict__ nb2,
         const bf16* __restrict__ wt, float* __restrict__ node_out)
{
  extern __shared__ char smem[];
  bf16* w3f = (bf16*)smem;              // 64 frags (t*8+c) x 512 = 65,536 B
  bf16* w4f = (bf16*)(smem + 65536);    // 32 frags (t*4+c) x 512 = 32,768 B

  const int tid  = threadIdx.x;
  const int wave = tid >> 6, lane = tid & 63;
  const int ln15 = lane & 15, lq = lane >> 4;

  #pragma unroll
  for (int it = 0; it < 8; ++it) {
    int idx = it * 512 + tid;
    int f = idx >> 6, l = idx & 63;
    int t = f >> 3, c = f & 7;
    *(uint4*)&w3f[idx * 8] =
        *(const uint4*)&wt[NW1T_OFF + (t * 16 + (l & 15)) * 256 + c * 32 + (l >> 4) * 8];
  }
  #pragma unroll
  for (int it = 0; it < 4; ++it) {
    int idx = it * 512 + tid;
    int f = idx >> 6, l = idx & 63;
    int t = f >> 2, c = f & 3;
    *(uint4*)&w4f[idx * 8] =
        *(const uint4*)&wt[NW2T_OFF + (t * 16 + (l & 15)) * 128 + c * 32 + (l >> 4) * 8];
  }
  __syncthreads();

  f32x4 b3v[8]; float b4s[8];
  #pragma unroll
  for (int t = 0; t < 8; ++t) {
    b3v[t] = *(const f32x4*)&nb1[t * 16 + lq * 4];
    b4s[t] = nb2[t * 16 + ln15];
  }

  const int srcA = ln15 + ((lq & 1) << 5);
  const int srcB = srcA + 16;
  const bool lql = (lq < 2);

  for (int tile = blockIdx.x * 8 + wave; tile < N_EDGES / 32; tile += gridDim.x * 8) {
    const int e0 = tile * 32;
    int rrow[2];
    int nid[2][4];
    #pragma unroll
    for (int e = 0; e < 2; ++e) {
      rrow[e] = eidx[e0 + e * 16 + ln15];
      int4 q = *(const int4*)&eidx[N_EDGES + e0 + e * 16 + lq * 4];
      nid[e][0] = q.x; nid[e][1] = q.y; nid[e][2] = q.z; nid[e][3] = q.w;
    }

    // ---- G3^T: 8 K-chunks (x_row | edge_new) ----
    f32x4 acc[8][2];
    #pragma unroll
    for (int t = 0; t < 8; ++t)
      #pragma unroll
      for (int e = 0; e < 2; ++e)
        acc[t][e] = f32x4{0.f, 0.f, 0.f, 0.f};

    #pragma unroll
    for (int c = 0; c < 8; ++c) {
      bf16x8 bf[2];
      #pragma unroll
      for (int e = 0; e < 2; ++e) {
        const float* src;
        if (c < 4) src = x + (size_t)rrow[e] * 128 + c * 32 + lq * 8;
        else       src = edge_new + (size_t)(e0 + e * 16 + ln15) * 128 + (c - 4) * 32 + lq * 8;
        bf[e] = load_cvt8(src);
      }
      #pragma unroll
      for (int t = 0; t < 8; ++t) {
        bf16x8 af = *(const bf16x8*)&w3f[(t * 8 + c) * 512 + lane * 8];
        #pragma unroll
        for (int e = 0; e < 2; ++e)
          acc[t][e] = __builtin_amdgcn_mfma_f32_16x16x32_bf16(af, bf[e], acc[t][e], 0, 0, 0);
      }
    }

    uint32_t P[8][2][2];
    #pragma unroll
    for (int t = 0; t < 8; ++t)
      #pragma unroll
      for (int e = 0; e < 2; ++e) {
        float v0 = softplus_f(acc[t][e][0] + b3v[t][0]);
        float v1 = softplus_f(acc[t][e][1] + b3v[t][1]);
        float v2 = softplus_f(acc[t][e][2] + b3v[t][2]);
        float v3 = softplus_f(acc[t][e][3] + b3v[t][3]);
        P[t][e][0] = pack2(v0, v1);
        P[t][e][1] = pack2(v2, v3);
      }

    // ---- G4 (normal): A = shuffled C3, B = w4f ----
    f32x4 a4[8][2];
    #pragma unroll
    for (int t = 0; t < 8; ++t)
      #pragma unroll
      for (int e = 0; e < 2; ++e)
        a4[t][e] = f32x4{0.f, 0.f, 0.f, 0.f};

    #pragma unroll
    for (int c = 0; c < 4; ++c) {
      bf16x8 F[2];
      #pragma unroll
      for (int e = 0; e < 2; ++e) {
        int p0lo = __shfl((int)P[2 * c][e][0], srcA);
        int p0hi = __shfl((int)P[2 * c][e][1], srcA);
        int p1lo = __shfl((int)P[2 * c + 1][e][0], srcA);
        int p1hi = __shfl((int)P[2 * c + 1][e][1], srcA);
        int q0lo = __shfl((int)P[2 * c][e][0], srcB);
        int q0hi = __shfl((int)P[2 * c][e][1], srcB);
        int q1lo = __shfl((int)P[2 * c + 1][e][0], srcB);
        int q1hi = __shfl((int)P[2 * c + 1][e][1], srcB);
        uint4 u;
        u.x = lql ? (uint32_t)p0lo : (uint32_t)p1lo;
        u.y = lql ? (uint32_t)p0hi : (uint32_t)p1hi;
        u.z = lql ? (uint32_t)q0lo : (uint32_t)q1lo;
        u.w = lql ? (uint32_t)q0hi : (uint32_t)q1hi;
        F[e] = __builtin_bit_cast(bf16x8, u);
      }
      #pragma unroll
      for (int t = 0; t < 8; ++t) {
        bf16x8 bw = *(const bf16x8*)&w4f[(t * 4 + c) * 512 + lane * 8];
        #pragma unroll
        for (int e = 0; e < 2; ++e)
          a4[t][e] = __builtin_amdgcn_mfma_f32_16x16x32_bf16(F[e], bw, a4[t][e], 0, 0, 0);
      }
    }

    // ---- scatter: per instr 4 nodes x 16 contiguous cols (good 64B pattern) ----
    #pragma unroll
    for (int t = 0; t < 8; ++t)
      #pragma unroll
      for (int e = 0; e < 2; ++e)
        #pragma unroll
        for (int r = 0; r < 4; ++r) {
          float v = a4[t][e][r] + b4s[t];
          unsafeAtomicAdd(&node_out[(size_t)nid[e][r] * 128 + t * 16 + ln15], v);
        }
  }
}

extern "C" void kernel_launch(void* const* d_in, const int* in_sizes, int n_in,
                              void* d_out, int out_size, void* d_ws, size_t ws_size,
                              hipStream_t stream) {
  const float* x    = (const float*)d_in[0];
  const int*   eidx = (const int*)d_in[1];
  const float* ea   = (const float*)d_in[2];
  const float* nW1  = (const float*)d_in[3];
  const float* nb1  = (const float*)d_in[4];
  const float* nW2  = (const float*)d_in[5];
  const float* nb2  = (const float*)d_in[6];
  const float* eW1  = (const float*)d_in[7];
  const float* eb1  = (const float*)d_in[8];
  const float* eW2  = (const float*)d_in[9];
  const float* eb2  = (const float*)d_in[10];

  bf16*  wt        = (bf16*)d_ws;                 // 114,688 bf16 = 229,376 B
  float* out_nodes = (float*)d_out;               // [10000,128]
  float* out_edges = out_nodes + NODE_OUT;        // [640000,128]

  hipMemsetAsync(out_nodes, 0, NODE_OUT * sizeof(float), stream);
  transpose_weights<<<448, 256, 0, stream>>>(eW1, eW2, nW1, nW2, wt);
  edge_mlp<<<256, 512, 131072, stream>>>(x, eidx, ea, eb1, eb2, wt, out_edges);
  node_mlp<<<256, 512, 98304, stream>>>(x, eidx, out_edges, nb1, nb2, wt, out_nodes);
}

// Round 5
// 879.646 us; speedup vs baseline: 2.0586x; 2.0586x over previous
//
#include <hip/hip_runtime.h>
#include <cstdint>

#define N_NODES   10000
#define N_EDGES   640000
#define NODE_OUT  (N_NODES * 128)       // 1,280,000 node-output floats

typedef __bf16 bf16;
typedef bf16  bf16x8 __attribute__((ext_vector_type(8)));
typedef float f32x4  __attribute__((ext_vector_type(4)));

// ws layout (bf16 elements): transposed weights then bf16 copy of x
#define EW1T_OFF 0        // 128 x 384
#define EW2T_OFF 49152    // 128 x 128
#define NW1T_OFF 65536    // 128 x 256
#define NW2T_OFF 98304    // 128 x 128
#define XB_OFF   114688   // 10000 x 128 bf16 copy of x
#define WS_NEED_BYTES (229376 + 2560000)

// -------- weight convert+transpose: fp32 W[K][N] -> bf16 WT[N][K] --------
__global__ void transpose_weights(const float* __restrict__ eW1, const float* __restrict__ eW2,
                                  const float* __restrict__ nW1, const float* __restrict__ nW2,
                                  bf16* __restrict__ wt) {
  int gid = blockIdx.x * 256 + threadIdx.x;   // 448*256 = 114688 exactly
  const float* src; bf16* dst; int K, off;
  if (gid < 49152)      { src = eW1; dst = wt + EW1T_OFF; K = 384; off = gid; }
  else if (gid < 65536) { src = eW2; dst = wt + EW2T_OFF; K = 128; off = gid - 49152; }
  else if (gid < 98304) { src = nW1; dst = wt + NW1T_OFF; K = 256; off = gid - 65536; }
  else                  { src = nW2; dst = wt + NW2T_OFF; K = 128; off = gid - 98304; }
  int k = off >> 7, n = off & 127;
  dst[n * K + k] = (bf16)src[off];
}

__device__ __forceinline__ float softplus_f(float v) {
  return v > 20.f ? v : __logf(1.f + __expf(v));
}

// load 8 consecutive fp32 and round to a bf16x8 fragment
__device__ __forceinline__ bf16x8 load_cvt8(const float* __restrict__ src) {
  float4 f0 = *(const float4*)src;
  float4 f1 = *(const float4*)(src + 4);
  bf16x8 h;
  h[0] = (bf16)f0.x; h[1] = (bf16)f0.y; h[2] = (bf16)f0.z; h[3] = (bf16)f0.w;
  h[4] = (bf16)f1.x; h[5] = (bf16)f1.y; h[6] = (bf16)f1.z; h[7] = (bf16)f1.w;
  return h;
}

// one-time x -> bf16 copy (gathered ~128x each; bf16 halves gather bytes)
__global__ void convert_x(const float* __restrict__ x, bf16* __restrict__ xb) {
  int i = (blockIdx.x * 256 + threadIdx.x) * 8;   // 625*256*8 = 1,280,000 exactly
  *(bf16x8*)&xb[i] = load_cvt8(x + i);
}

// ============ edge MLP: GEMM1(K=384)+softplus, GEMM2(K=128) ============
// 512 thr = 8 waves; wave owns N-strip of 16 (n0 = wave*16), full M=32 tile.
// Weights register-resident: w1[12] + w2[4] bf16x8 = 64 VGPRs.
// sA [32 rows][48 slots of 16B], physical slot = logical ^ (row&7); sC [32][128].
// 2 barriers per tile (hazard proof: S2 separates G1-reads from staging(t+1);
// S1(t+1) separates G2-reads of sC from epi(t+1) writes).
template<bool XB>
__global__ void __launch_bounds__(512, 4)
edge_mlp(const float* __restrict__ x, const bf16* __restrict__ xb,
         const int* __restrict__ eidx, const float* __restrict__ edge_attr,
         const float* __restrict__ eb1, const float* __restrict__ eb2,
         const bf16* __restrict__ wt, float* __restrict__ edge_out)
{
  __shared__ bf16 sA[32 * 384];   // 24,576 B : slots 0-15 x_row | 16-31 x_col | 32-47 ea
  __shared__ bf16 sC[32 * 128];   //  8,192 B : C1, swizzled

  const int tid  = threadIdx.x;
  const int wave = tid >> 6, lane = tid & 63;
  const int ln15 = lane & 15, lq = lane >> 4;
  const int n0 = wave * 16;
  const int sw = ln15 & 7;

  bf16x8 w1[12], w2[4];
  #pragma unroll
  for (int c = 0; c < 12; ++c)
    w1[c] = *(const bf16x8*)&wt[EW1T_OFF + (n0 + ln15) * 384 + c * 32 + lq * 8];
  #pragma unroll
  for (int c = 0; c < 4; ++c)
    w2[c] = *(const bf16x8*)&wt[EW2T_OFF + (n0 + ln15) * 128 + c * 32 + lq * 8];
  const float b1 = eb1[n0 + ln15];
  const float b2 = eb2[n0 + ln15];

  const int se = tid >> 4;        // staging edge 0..31 (16 thr per edge)
  const int pl = tid & 15;        // physical slot within region
  const int lp = pl ^ (se & 7);   // logical slot this thread stages

  for (int tile = blockIdx.x; tile < N_EDGES / 32; tile += gridDim.x) {
    const int e0 = tile * 32;

    // ---- stage sA: 3 regions x 512 chunks, one pass each ----
    {
      int ri = eidx[e0 + se];
      int ci = eidx[N_EDGES + e0 + se];
      if constexpr (XB) {
        *(uint4*)&sA[se * 384 + (0 * 16 + pl) * 8] = *(const uint4*)&xb[(size_t)ri * 128 + lp * 8];
        *(uint4*)&sA[se * 384 + (1 * 16 + pl) * 8] = *(const uint4*)&xb[(size_t)ci * 128 + lp * 8];
      } else {
        *(bf16x8*)&sA[se * 384 + (0 * 16 + pl) * 8] = load_cvt8(x + (size_t)ri * 128 + lp * 8);
        *(bf16x8*)&sA[se * 384 + (1 * 16 + pl) * 8] = load_cvt8(x + (size_t)ci * 128 + lp * 8);
      }
      *(bf16x8*)&sA[se * 384 + (2 * 16 + pl) * 8] =
          load_cvt8(edge_attr + (size_t)(e0 + se) * 128 + lp * 8);
    }
    __syncthreads();   // S1

    // ---- G1: sA @ w1 ----
    f32x4 acc0 = {0.f, 0.f, 0.f, 0.f}, acc1 = {0.f, 0.f, 0.f, 0.f};
    #pragma unroll
    for (int c = 0; c < 12; ++c) {
      int s = c * 4 + lq;
      bf16x8 a0 = *(const bf16x8*)&sA[ln15 * 384 + ((s ^ sw) << 3)];
      bf16x8 a1 = *(const bf16x8*)&sA[(16 + ln15) * 384 + ((s ^ sw) << 3)];
      acc0 = __builtin_amdgcn_mfma_f32_16x16x32_bf16(a0, w1[c], acc0, 0, 0, 0);
      acc1 = __builtin_amdgcn_mfma_f32_16x16x32_bf16(a1, w1[c], acc1, 0, 0, 0);
    }

    // ---- C1 = softplus(acc + b1) -> sC ----
    #pragma unroll
    for (int mf = 0; mf < 2; ++mf)
      #pragma unroll
      for (int r = 0; r < 4; ++r) {
        float v = softplus_f((mf ? acc1[r] : acc0[r]) + b1);
        int row = mf * 16 + lq * 4 + r;
        int col = n0 + ln15;
        sC[row * 128 + ((((col >> 3) ^ (row & 7))) << 3) + (col & 7)] = (bf16)v;
      }
    __syncthreads();   // S2

    // ---- G2: sC @ w2 -> edge_out ----
    f32x4 d0 = {0.f, 0.f, 0.f, 0.f}, d1 = {0.f, 0.f, 0.f, 0.f};
    #pragma unroll
    for (int c = 0; c < 4; ++c) {
      int s = c * 4 + lq;
      bf16x8 a0 = *(const bf16x8*)&sC[ln15 * 128 + ((s ^ sw) << 3)];
      bf16x8 a1 = *(const bf16x8*)&sC[(16 + ln15) * 128 + ((s ^ sw) << 3)];
      d0 = __builtin_amdgcn_mfma_f32_16x16x32_bf16(a0, w2[c], d0, 0, 0, 0);
      d1 = __builtin_amdgcn_mfma_f32_16x16x32_bf16(a1, w2[c], d1, 0, 0, 0);
    }
    #pragma unroll
    for (int mf = 0; mf < 2; ++mf)
      #pragma unroll
      for (int r = 0; r < 4; ++r) {
        int row = mf * 16 + lq * 4 + r;
        edge_out[(size_t)(e0 + row) * 128 + n0 + ln15] = (mf ? d1[r] : d0[r]) + b2;
      }
  }
}

// ============ node MLP: GEMM3(K=256)+softplus, GEMM4(K=128)+scatter ============
template<bool XB>
__global__ void __launch_bounds__(512, 4)
node_mlp(const float* __restrict__ x, const bf16* __restrict__ xb,
         const int* __restrict__ eidx, const float* __restrict__ edge_new,
         const float* __restrict__ nb1, const float* __restrict__ nb2,
         const bf16* __restrict__ wt, float* __restrict__ node_out)
{
  __shared__ bf16 sA[32 * 384];   // slots 0-15 x_row | 16-31 C2 | 32-47 C3

  const int tid  = threadIdx.x;
  const int wave = tid >> 6, lane = tid & 63;
  const int ln15 = lane & 15, lq = lane >> 4;
  const int n0 = wave * 16;
  const int sw = ln15 & 7;

  bf16x8 w3[8], w4[4];
  #pragma unroll
  for (int c = 0; c < 8; ++c)
    w3[c] = *(const bf16x8*)&wt[NW1T_OFF + (n0 + ln15) * 256 + c * 32 + lq * 8];
  #pragma unroll
  for (int c = 0; c < 4; ++c)
    w4[c] = *(const bf16x8*)&wt[NW2T_OFF + (n0 + ln15) * 128 + c * 32 + lq * 8];
  const float b3 = nb1[n0 + ln15];
  const float b4 = nb2[n0 + ln15];

  const int se = tid >> 4;
  const int pl = tid & 15;
  const int lp = pl ^ (se & 7);

  for (int tile = blockIdx.x; tile < N_EDGES / 32; tile += gridDim.x) {
    const int e0 = tile * 32;

    // ---- stage slots 0-31: x_row gather | C2 (= edge_new fp32) ----
    {
      int ri = eidx[e0 + se];
      if constexpr (XB)
        *(uint4*)&sA[se * 384 + (0 * 16 + pl) * 8] = *(const uint4*)&xb[(size_t)ri * 128 + lp * 8];
      else
        *(bf16x8*)&sA[se * 384 + (0 * 16 + pl) * 8] = load_cvt8(x + (size_t)ri * 128 + lp * 8);
      *(bf16x8*)&sA[se * 384 + (1 * 16 + pl) * 8] =
          load_cvt8(edge_new + (size_t)(e0 + se) * 128 + lp * 8);
    }
    __syncthreads();   // S1

    // ---- G3: sA[0..31] @ w3 ----
    f32x4 acc0 = {0.f, 0.f, 0.f, 0.f}, acc1 = {0.f, 0.f, 0.f, 0.f};
    #pragma unroll
    for (int c = 0; c < 8; ++c) {
      int s = c * 4 + lq;
      bf16x8 a0 = *(const bf16x8*)&sA[ln15 * 384 + ((s ^ sw) << 3)];
      bf16x8 a1 = *(const bf16x8*)&sA[(16 + ln15) * 384 + ((s ^ sw) << 3)];
      acc0 = __builtin_amdgcn_mfma_f32_16x16x32_bf16(a0, w3[c], acc0, 0, 0, 0);
      acc1 = __builtin_amdgcn_mfma_f32_16x16x32_bf16(a1, w3[c], acc1, 0, 0, 0);
    }

    // ---- C3 = softplus(acc + b3) -> slots 32-47 (disjoint from G3 reads) ----
    #pragma unroll
    for (int mf = 0; mf < 2; ++mf)
      #pragma unroll
      for (int r = 0; r < 4; ++r) {
        float v = softplus_f((mf ? acc1[r] : acc0[r]) + b3);
        int row = mf * 16 + lq * 4 + r;
        int col = n0 + ln15;
        int ls  = 32 + (col >> 3);
        sA[row * 384 + ((ls ^ (row & 7)) << 3) + (col & 7)] = (bf16)v;
      }
    __syncthreads();   // S2

    // ---- G4: sA[32..47] @ w4 -> atomic scatter ----
    f32x4 d0 = {0.f, 0.f, 0.f, 0.f}, d1 = {0.f, 0.f, 0.f, 0.f};
    #pragma unroll
    for (int c = 0; c < 4; ++c) {
      int s = 32 + c * 4 + lq;
      bf16x8 a0 = *(const bf16x8*)&sA[ln15 * 384 + ((s ^ sw) << 3)];
      bf16x8 a1 = *(const bf16x8*)&sA[(16 + ln15) * 384 + ((s ^ sw) << 3)];
      d0 = __builtin_amdgcn_mfma_f32_16x16x32_bf16(a0, w4[c], d0, 0, 0, 0);
      d1 = __builtin_amdgcn_mfma_f32_16x16x32_bf16(a1, w4[c], d1, 0, 0, 0);
    }
    #pragma unroll
    for (int mf = 0; mf < 2; ++mf) {
      int4 q = *(const int4*)&eidx[N_EDGES + e0 + mf * 16 + lq * 4];
      int nid[4] = {q.x, q.y, q.z, q.w};
      #pragma unroll
      for (int r = 0; r < 4; ++r) {
        float v = (mf ? d1[r] : d0[r]) + b4;
        unsafeAtomicAdd(&node_out[(size_t)nid[r] * 128 + n0 + ln15], v);
      }
    }
  }
}

extern "C" void kernel_launch(void* const* d_in, const int* in_sizes, int n_in,
                              void* d_out, int out_size, void* d_ws, size_t ws_size,
                              hipStream_t stream) {
  const float* x    = (const float*)d_in[0];
  const int*   eidx = (const int*)d_in[1];
  const float* ea   = (const float*)d_in[2];
  const float* nW1  = (const float*)d_in[3];
  const float* nb1  = (const float*)d_in[4];
  const float* nW2  = (const float*)d_in[5];
  const float* nb2  = (const float*)d_in[6];
  const float* eW1  = (const float*)d_in[7];
  const float* eb1  = (const float*)d_in[8];
  const float* eW2  = (const float*)d_in[9];
  const float* eb2  = (const float*)d_in[10];

  bf16*  wt        = (bf16*)d_ws;                 // weights + optional xb
  float* out_nodes = (float*)d_out;               // [10000,128]
  float* out_edges = out_nodes + NODE_OUT;        // [640000,128]

  hipMemsetAsync(out_nodes, 0, NODE_OUT * sizeof(float), stream);
  transpose_weights<<<448, 256, 0, stream>>>(eW1, eW2, nW1, nW2, wt);

  const bool use_xb = ws_size >= (size_t)WS_NEED_BYTES;
  bf16* xb = wt + XB_OFF;
  if (use_xb) {
    convert_x<<<625, 256, 0, stream>>>(x, xb);
    edge_mlp<true><<<512, 512, 0, stream>>>(x, xb, eidx, ea, eb1, eb2, wt, out_edges);
    node_mlp<true><<<512, 512, 0, stream>>>(x, xb, eidx, out_edges, nb1, nb2, wt, out_nodes);
  } else {
    edge_mlp<false><<<512, 512, 0, stream>>>(x, nullptr, eidx, ea, eb1, eb2, wt, out_edges);
    node_mlp<false><<<512, 512, 0, stream>>>(x, nullptr, eidx, out_edges, nb1, nb2, wt, out_nodes);
  }
}

// Round 7
// 839.182 us; speedup vs baseline: 2.1578x; 1.0482x over previous
//
#include <hip/hip_runtime.h>
#include <cstdint>

#define N_NODES   10000
#define N_EDGES   640000
#define NODE_OUT  (N_NODES * 128)       // 1,280,000 node-output floats

typedef __bf16 bf16;
typedef bf16  bf16x8 __attribute__((ext_vector_type(8)));
typedef float f32x4  __attribute__((ext_vector_type(4)));

// ws layout (bf16 elements): transposed weights then bf16 copy of x
#define EW1T_OFF 0        // 128 x 384
#define EW2T_OFF 49152    // 128 x 128
#define NW1T_OFF 65536    // 128 x 256
#define NW2T_OFF 98304    // 128 x 128
#define XB_OFF   114688   // 10000 x 128 bf16 copy of x
#define WS_NEED_BYTES (229376 + 2560000)

// -------- weight convert+transpose: fp32 W[K][N] -> bf16 WT[N][K] --------
__global__ void transpose_weights(const float* __restrict__ eW1, const float* __restrict__ eW2,
                                  const float* __restrict__ nW1, const float* __restrict__ nW2,
                                  bf16* __restrict__ wt) {
  int gid = blockIdx.x * 256 + threadIdx.x;   // 448*256 = 114688 exactly
  const float* src; bf16* dst; int K, off;
  if (gid < 49152)      { src = eW1; dst = wt + EW1T_OFF; K = 384; off = gid; }
  else if (gid < 65536) { src = eW2; dst = wt + EW2T_OFF; K = 128; off = gid - 49152; }
  else if (gid < 98304) { src = nW1; dst = wt + NW1T_OFF; K = 256; off = gid - 65536; }
  else                  { src = nW2; dst = wt + NW2T_OFF; K = 128; off = gid - 98304; }
  int k = off >> 7, n = off & 127;
  dst[n * K + k] = (bf16)src[off];
}

__device__ __forceinline__ float softplus_f(float v) {
  return v > 20.f ? v : __logf(1.f + __expf(v));
}

__device__ __forceinline__ bf16x8 cvt8(float4 f0, float4 f1) {
  bf16x8 h;
  h[0] = (bf16)f0.x; h[1] = (bf16)f0.y; h[2] = (bf16)f0.z; h[3] = (bf16)f0.w;
  h[4] = (bf16)f1.x; h[5] = (bf16)f1.y; h[6] = (bf16)f1.z; h[7] = (bf16)f1.w;
  return h;
}

// load 8 consecutive fp32 and round to a bf16x8 fragment
__device__ __forceinline__ bf16x8 load_cvt8(const float* __restrict__ src) {
  float4 f0 = *(const float4*)src;
  float4 f1 = *(const float4*)(src + 4);
  return cvt8(f0, f1);
}

// one-time x -> bf16 copy (gathered ~128x each; bf16 halves gather bytes)
__global__ void convert_x(const float* __restrict__ x, bf16* __restrict__ xb) {
  int i = (blockIdx.x * 256 + threadIdx.x) * 8;   // 625*256*8 = 1,280,000 exactly
  *(bf16x8*)&xb[i] = load_cvt8(x + i);
}

// ============ edge MLP: GEMM1(K=384)+softplus, GEMM2(K=128) ============
// 256 thr = 4 waves; wave owns N-strip of 32 (n0 = wave*32), full M=32 tile.
// Weights register-resident: w1[12][2] + w2[4][2] = 128 VGPRs.
// Software-pipelined staging (T14): regs hold tile t+1's gathers during tile t compute.
// 2 barriers/tile; regs->LDS commit at loop top touches sA only (G2 reads sC: disjoint).
template<bool XB>
__global__ void __launch_bounds__(256, 2)
edge_mlp(const float* __restrict__ x, const bf16* __restrict__ xb,
         const int* __restrict__ eidx, const float* __restrict__ edge_attr,
         const float* __restrict__ eb1, const float* __restrict__ eb2,
         const bf16* __restrict__ wt, float* __restrict__ edge_out)
{
  __shared__ bf16 sA[32 * 384];   // 24,576 B : slots 0-15 x_row | 16-31 x_col | 32-47 ea
  __shared__ bf16 sC[32 * 128];   //  8,192 B : C1, swizzled

  const int tid  = threadIdx.x;
  const int wave = tid >> 6, lane = tid & 63;
  const int ln15 = lane & 15, lq = lane >> 4;
  const int n0 = wave * 32;
  const int sw = ln15 & 7;

  bf16x8 w1[12][2], w2[4][2];
  #pragma unroll
  for (int c = 0; c < 12; ++c)
    #pragma unroll
    for (int t = 0; t < 2; ++t)
      w1[c][t] = *(const bf16x8*)&wt[EW1T_OFF + (n0 + t * 16 + ln15) * 384 + c * 32 + lq * 8];
  #pragma unroll
  for (int c = 0; c < 4; ++c)
    #pragma unroll
    for (int t = 0; t < 2; ++t)
      w2[c][t] = *(const bf16x8*)&wt[EW2T_OFF + (n0 + t * 16 + ln15) * 128 + c * 32 + lq * 8];
  float b1[2], b2[2];
  #pragma unroll
  for (int t = 0; t < 2; ++t) {
    b1[t] = eb1[n0 + t * 16 + ln15];
    b2[t] = eb2[n0 + t * 16 + ln15];
  }

  // staging geometry: 16 threads per edge; this thread stages edges eA and eA+16,
  // physical slot pl, logical slot lp = pl ^ (e&7)  (eA&7 == eB&7)
  const int eA = tid >> 4, eB = eA + 16;
  const int pl = tid & 15, lp = pl ^ (eA & 7);

  // staged register state for one tile
  uint4  hx0, hx1, hc0, hc1;            // XB path: raw bf16x8 of x_row/x_col
  float4 px0[2], px1[2], pc0[2], pc1[2]; // !XB path: fp32 x_row/x_col
  float4 pa0[2], pa1[2];                 // edge_attr fp32 (always)

  const int NT = N_EDGES / 32;

  // ---- prologue: issue loads for tile0 ----
  {
    const int e0 = blockIdx.x * 32;
    int riA = eidx[e0 + eA], riB = eidx[e0 + eB];
    int ciA = eidx[N_EDGES + e0 + eA], ciB = eidx[N_EDGES + e0 + eB];
    if constexpr (XB) {
      hx0 = *(const uint4*)&xb[(size_t)riA * 128 + lp * 8];
      hx1 = *(const uint4*)&xb[(size_t)riB * 128 + lp * 8];
      hc0 = *(const uint4*)&xb[(size_t)ciA * 128 + lp * 8];
      hc1 = *(const uint4*)&xb[(size_t)ciB * 128 + lp * 8];
    } else {
      px0[0] = *(const float4*)(x + (size_t)riA * 128 + lp * 8);
      px0[1] = *(const float4*)(x + (size_t)riA * 128 + lp * 8 + 4);
      px1[0] = *(const float4*)(x + (size_t)riB * 128 + lp * 8);
      px1[1] = *(const float4*)(x + (size_t)riB * 128 + lp * 8 + 4);
      pc0[0] = *(const float4*)(x + (size_t)ciA * 128 + lp * 8);
      pc0[1] = *(const float4*)(x + (size_t)ciA * 128 + lp * 8 + 4);
      pc1[0] = *(const float4*)(x + (size_t)ciB * 128 + lp * 8);
      pc1[1] = *(const float4*)(x + (size_t)ciB * 128 + lp * 8 + 4);
    }
    pa0[0] = *(const float4*)(edge_attr + (size_t)(e0 + eA) * 128 + lp * 8);
    pa0[1] = *(const float4*)(edge_attr + (size_t)(e0 + eA) * 128 + lp * 8 + 4);
    pa1[0] = *(const float4*)(edge_attr + (size_t)(e0 + eB) * 128 + lp * 8);
    pa1[1] = *(const float4*)(edge_attr + (size_t)(e0 + eB) * 128 + lp * 8 + 4);
  }

  for (int tile = blockIdx.x; tile < NT; tile += gridDim.x) {
    const int e0 = tile * 32;

    // ---- commit staged regs -> sA (disjoint from sC which prev G2 read) ----
    if constexpr (XB) {
      *(uint4*)&sA[eA * 384 + (0 * 16 + pl) * 8] = hx0;
      *(uint4*)&sA[eB * 384 + (0 * 16 + pl) * 8] = hx1;
      *(uint4*)&sA[eA * 384 + (1 * 16 + pl) * 8] = hc0;
      *(uint4*)&sA[eB * 384 + (1 * 16 + pl) * 8] = hc1;
    } else {
      *(bf16x8*)&sA[eA * 384 + (0 * 16 + pl) * 8] = cvt8(px0[0], px0[1]);
      *(bf16x8*)&sA[eB * 384 + (0 * 16 + pl) * 8] = cvt8(px1[0], px1[1]);
      *(bf16x8*)&sA[eA * 384 + (1 * 16 + pl) * 8] = cvt8(pc0[0], pc0[1]);
      *(bf16x8*)&sA[eB * 384 + (1 * 16 + pl) * 8] = cvt8(pc1[0], pc1[1]);
    }
    *(bf16x8*)&sA[eA * 384 + (2 * 16 + pl) * 8] = cvt8(pa0[0], pa0[1]);
    *(bf16x8*)&sA[eB * 384 + (2 * 16 + pl) * 8] = cvt8(pa1[0], pa1[1]);

    // ---- issue next-tile loads (fly under this tile's compute) ----
    const int tn = tile + gridDim.x;
    if (tn < NT) {
      const int en = tn * 32;
      int riA = eidx[en + eA], riB = eidx[en + eB];
      int ciA = eidx[N_EDGES + en + eA], ciB = eidx[N_EDGES + en + eB];
      if constexpr (XB) {
        hx0 = *(const uint4*)&xb[(size_t)riA * 128 + lp * 8];
        hx1 = *(const uint4*)&xb[(size_t)riB * 128 + lp * 8];
        hc0 = *(const uint4*)&xb[(size_t)ciA * 128 + lp * 8];
        hc1 = *(const uint4*)&xb[(size_t)ciB * 128 + lp * 8];
      } else {
        px0[0] = *(const float4*)(x + (size_t)riA * 128 + lp * 8);
        px0[1] = *(const float4*)(x + (size_t)riA * 128 + lp * 8 + 4);
        px1[0] = *(const float4*)(x + (size_t)riB * 128 + lp * 8);
        px1[1] = *(const float4*)(x + (size_t)riB * 128 + lp * 8 + 4);
        pc0[0] = *(const float4*)(x + (size_t)ciA * 128 + lp * 8);
        pc0[1] = *(const float4*)(x + (size_t)ciA * 128 + lp * 8 + 4);
        pc1[0] = *(const float4*)(x + (size_t)ciB * 128 + lp * 8);
        pc1[1] = *(const float4*)(x + (size_t)ciB * 128 + lp * 8 + 4);
      }
      pa0[0] = *(const float4*)(edge_attr + (size_t)(en + eA) * 128 + lp * 8);
      pa0[1] = *(const float4*)(edge_attr + (size_t)(en + eA) * 128 + lp * 8 + 4);
      pa1[0] = *(const float4*)(edge_attr + (size_t)(en + eB) * 128 + lp * 8);
      pa1[1] = *(const float4*)(edge_attr + (size_t)(en + eB) * 128 + lp * 8 + 4);
    }
    __syncthreads();   // S1: sA visible

    // ---- G1: sA @ w1 ----
    f32x4 acc[2][2];
    #pragma unroll
    for (int mf = 0; mf < 2; ++mf)
      #pragma unroll
      for (int t = 0; t < 2; ++t)
        acc[mf][t] = f32x4{0.f, 0.f, 0.f, 0.f};
    #pragma unroll
    for (int c = 0; c < 12; ++c) {
      int s = (((c * 4 + lq) ^ sw) << 3);
      bf16x8 a0 = *(const bf16x8*)&sA[ln15 * 384 + s];
      bf16x8 a1 = *(const bf16x8*)&sA[(16 + ln15) * 384 + s];
      #pragma unroll
      for (int t = 0; t < 2; ++t) {
        acc[0][t] = __builtin_amdgcn_mfma_f32_16x16x32_bf16(a0, w1[c][t], acc[0][t], 0, 0, 0);
        acc[1][t] = __builtin_amdgcn_mfma_f32_16x16x32_bf16(a1, w1[c][t], acc[1][t], 0, 0, 0);
      }
    }

    // ---- C1 = softplus(acc + b1) -> sC ----
    #pragma unroll
    for (int mf = 0; mf < 2; ++mf)
      #pragma unroll
      for (int t = 0; t < 2; ++t)
        #pragma unroll
        for (int r = 0; r < 4; ++r) {
          float v = softplus_f(acc[mf][t][r] + b1[t]);
          int row = mf * 16 + lq * 4 + r;
          int col = n0 + t * 16 + ln15;
          sC[row * 128 + ((((col >> 3) ^ (row & 7))) << 3) + (col & 7)] = (bf16)v;
        }
    __syncthreads();   // S2: C1 visible

    // ---- G2: sC @ w2 -> edge_out ----
    f32x4 d[2][2];
    #pragma unroll
    for (int mf = 0; mf < 2; ++mf)
      #pragma unroll
      for (int t = 0; t < 2; ++t)
        d[mf][t] = f32x4{0.f, 0.f, 0.f, 0.f};
    #pragma unroll
    for (int c = 0; c < 4; ++c) {
      int s = (((c * 4 + lq) ^ sw) << 3);
      bf16x8 a0 = *(const bf16x8*)&sC[ln15 * 128 + s];
      bf16x8 a1 = *(const bf16x8*)&sC[(16 + ln15) * 128 + s];
      #pragma unroll
      for (int t = 0; t < 2; ++t) {
        d[0][t] = __builtin_amdgcn_mfma_f32_16x16x32_bf16(a0, w2[c][t], d[0][t], 0, 0, 0);
        d[1][t] = __builtin_amdgcn_mfma_f32_16x16x32_bf16(a1, w2[c][t], d[1][t], 0, 0, 0);
      }
    }
    #pragma unroll
    for (int mf = 0; mf < 2; ++mf)
      #pragma unroll
      for (int t = 0; t < 2; ++t)
        #pragma unroll
        for (int r = 0; r < 4; ++r) {
          int row = mf * 16 + lq * 4 + r;
          edge_out[(size_t)(e0 + row) * 128 + n0 + t * 16 + ln15] = d[mf][t][r] + b2[t];
        }
  }
}

// ============ node MLP: GEMM3(K=256)+softplus, GEMM4(K=128)+scatter ============
template<bool XB>
__global__ void __launch_bounds__(256, 2)
node_mlp(const float* __restrict__ x, const bf16* __restrict__ xb,
         const int* __restrict__ eidx, const float* __restrict__ edge_new,
         const float* __restrict__ nb1, const float* __restrict__ nb2,
         const bf16* __restrict__ wt, float* __restrict__ node_out)
{
  __shared__ bf16 sA[32 * 384];   // slots 0-15 x_row | 16-31 C2 | 32-47 C3

  const int tid  = threadIdx.x;
  const int wave = tid >> 6, lane = tid & 63;
  const int ln15 = lane & 15, lq = lane >> 4;
  const int n0 = wave * 32;
  const int sw = ln15 & 7;

  bf16x8 w3[8][2], w4[4][2];
  #pragma unroll
  for (int c = 0; c < 8; ++c)
    #pragma unroll
    for (int t = 0; t < 2; ++t)
      w3[c][t] = *(const bf16x8*)&wt[NW1T_OFF + (n0 + t * 16 + ln15) * 256 + c * 32 + lq * 8];
  #pragma unroll
  for (int c = 0; c < 4; ++c)
    #pragma unroll
    for (int t = 0; t < 2; ++t)
      w4[c][t] = *(const bf16x8*)&wt[NW2T_OFF + (n0 + t * 16 + ln15) * 128 + c * 32 + lq * 8];
  float b3[2], b4[2];
  #pragma unroll
  for (int t = 0; t < 2; ++t) {
    b3[t] = nb1[n0 + t * 16 + ln15];
    b4[t] = nb2[n0 + t * 16 + ln15];
  }

  const int eA = tid >> 4, eB = eA + 16;
  const int pl = tid & 15, lp = pl ^ (eA & 7);

  uint4  hx0, hx1;                 // XB path x_row
  float4 px0[2], px1[2];           // !XB path x_row
  float4 pe0[2], pe1[2];           // edge_new fp32

  const int NT = N_EDGES / 32;

  // ---- prologue ----
  {
    const int e0 = blockIdx.x * 32;
    int riA = eidx[e0 + eA], riB = eidx[e0 + eB];
    if constexpr (XB) {
      hx0 = *(const uint4*)&xb[(size_t)riA * 128 + lp * 8];
      hx1 = *(const uint4*)&xb[(size_t)riB * 128 + lp * 8];
    } else {
      px0[0] = *(const float4*)(x + (size_t)riA * 128 + lp * 8);
      px0[1] = *(const float4*)(x + (size_t)riA * 128 + lp * 8 + 4);
      px1[0] = *(const float4*)(x + (size_t)riB * 128 + lp * 8);
      px1[1] = *(const float4*)(x + (size_t)riB * 128 + lp * 8 + 4);
    }
    pe0[0] = *(const float4*)(edge_new + (size_t)(e0 + eA) * 128 + lp * 8);
    pe0[1] = *(const float4*)(edge_new + (size_t)(e0 + eA) * 128 + lp * 8 + 4);
    pe1[0] = *(const float4*)(edge_new + (size_t)(e0 + eB) * 128 + lp * 8);
    pe1[1] = *(const float4*)(edge_new + (size_t)(e0 + eB) * 128 + lp * 8 + 4);
  }

  for (int tile = blockIdx.x; tile < NT; tile += gridDim.x) {
    const int e0 = tile * 32;

    // ---- commit staged regs -> slots 0-31 (disjoint from slots 32-47 read by prev G4) ----
    if constexpr (XB) {
      *(uint4*)&sA[eA * 384 + (0 * 16 + pl) * 8] = hx0;
      *(uint4*)&sA[eB * 384 + (0 * 16 + pl) * 8] = hx1;
    } else {
      *(bf16x8*)&sA[eA * 384 + (0 * 16 + pl) * 8] = cvt8(px0[0], px0[1]);
      *(bf16x8*)&sA[eB * 384 + (0 * 16 + pl) * 8] = cvt8(px1[0], px1[1]);
    }
    *(bf16x8*)&sA[eA * 384 + (1 * 16 + pl) * 8] = cvt8(pe0[0], pe0[1]);
    *(bf16x8*)&sA[eB * 384 + (1 * 16 + pl) * 8] = cvt8(pe1[0], pe1[1]);

    // ---- issue next-tile loads ----
    const int tn = tile + gridDim.x;
    if (tn < NT) {
      const int en = tn * 32;
      int riA = eidx[en + eA], riB = eidx[en + eB];
      if constexpr (XB) {
        hx0 = *(const uint4*)&xb[(size_t)riA * 128 + lp * 8];
        hx1 = *(const uint4*)&xb[(size_t)riB * 128 + lp * 8];
      } else {
        px0[0] = *(const float4*)(x + (size_t)riA * 128 + lp * 8);
        px0[1] = *(const float4*)(x + (size_t)riA * 128 + lp * 8 + 4);
        px1[0] = *(const float4*)(x + (size_t)riB * 128 + lp * 8);
        px1[1] = *(const float4*)(x + (size_t)riB * 128 + lp * 8 + 4);
      }
      pe0[0] = *(const float4*)(edge_new + (size_t)(en + eA) * 128 + lp * 8);
      pe0[1] = *(const float4*)(edge_new + (size_t)(en + eA) * 128 + lp * 8 + 4);
      pe1[0] = *(const float4*)(edge_new + (size_t)(en + eB) * 128 + lp * 8);
      pe1[1] = *(const float4*)(edge_new + (size_t)(en + eB) * 128 + lp * 8 + 4);
    }
    __syncthreads();   // S1

    // ---- G3: sA[0..31] @ w3 ----
    f32x4 acc[2][2];
    #pragma unroll
    for (int mf = 0; mf < 2; ++mf)
      #pragma unroll
      for (int t = 0; t < 2; ++t)
        acc[mf][t] = f32x4{0.f, 0.f, 0.f, 0.f};
    #pragma unroll
    for (int c = 0; c < 8; ++c) {
      int s = (((c * 4 + lq) ^ sw) << 3);
      bf16x8 a0 = *(const bf16x8*)&sA[ln15 * 384 + s];
      bf16x8 a1 = *(const bf16x8*)&sA[(16 + ln15) * 384 + s];
      #pragma unroll
      for (int t = 0; t < 2; ++t) {
        acc[0][t] = __builtin_amdgcn_mfma_f32_16x16x32_bf16(a0, w3[c][t], acc[0][t], 0, 0, 0);
        acc[1][t] = __builtin_amdgcn_mfma_f32_16x16x32_bf16(a1, w3[c][t], acc[1][t], 0, 0, 0);
      }
    }

    // ---- C3 = softplus(acc + b3) -> slots 32-47 ----
    #pragma unroll
    for (int mf = 0; mf < 2; ++mf)
      #pragma unroll
      for (int t = 0; t < 2; ++t)
        #pragma unroll
        for (int r = 0; r < 4; ++r) {
          float v = softplus_f(acc[mf][t][r] + b3[t]);
          int row = mf * 16 + lq * 4 + r;
          int col = n0 + t * 16 + ln15;
          int ls  = 32 + (col >> 3);
          sA[row * 384 + ((ls ^ (row & 7)) << 3) + (col & 7)] = (bf16)v;
        }
    __syncthreads();   // S2

    // ---- G4: sA[32..47] @ w4 -> atomic scatter ----
    f32x4 d[2][2];
    #pragma unroll
    for (int mf = 0; mf < 2; ++mf)
      #pragma unroll
      for (int t = 0; t < 2; ++t)
        d[mf][t] = f32x4{0.f, 0.f, 0.f, 0.f};
    #pragma unroll
    for (int c = 0; c < 4; ++c) {
      int s = (((32 + c * 4 + lq) ^ sw) << 3);
      bf16x8 a0 = *(const bf16x8*)&sA[ln15 * 384 + s];
      bf16x8 a1 = *(const bf16x8*)&sA[(16 + ln15) * 384 + s];
      #pragma unroll
      for (int t = 0; t < 2; ++t) {
        d[0][t] = __builtin_amdgcn_mfma_f32_16x16x32_bf16(a0, w4[c][t], d[0][t], 0, 0, 0);
        d[1][t] = __builtin_amdgcn_mfma_f32_16x16x32_bf16(a1, w4[c][t], d[1][t], 0, 0, 0);
      }
    }
    #pragma unroll
    for (int mf = 0; mf < 2; ++mf) {
      int4 q = *(const int4*)&eidx[N_EDGES + e0 + mf * 16 + lq * 4];
      int nid[4] = {q.x, q.y, q.z, q.w};
      #pragma unroll
      for (int t = 0; t < 2; ++t) {
        int col = n0 + t * 16 + ln15;
        #pragma unroll
        for (int r = 0; r < 4; ++r) {
          float v = d[mf][t][r] + b4[t];
          unsafeAtomicAdd(&node_out[(size_t)nid[r] * 128 + col], v);
        }
      }
    }
  }
}

extern "C" void kernel_launch(void* const* d_in, const int* in_sizes, int n_in,
                              void* d_out, int out_size, void* d_ws, size_t ws_size,
                              hipStream_t stream) {
  const float* x    = (const float*)d_in[0];
  const int*   eidx = (const int*)d_in[1];
  const float* ea   = (const float*)d_in[2];
  const float* nW1  = (const float*)d_in[3];
  const float* nb1  = (const float*)d_in[4];
  const float* nW2  = (const float*)d_in[5];
  const float* nb2  = (const float*)d_in[6];
  const float* eW1  = (const float*)d_in[7];
  const float* eb1  = (const float*)d_in[8];
  const float* eW2  = (const float*)d_in[9];
  const float* eb2  = (const float*)d_in[10];

  bf16*  wt        = (bf16*)d_ws;                 // weights + optional xb
  float* out_nodes = (float*)d_out;               // [10000,128]
  float* out_edges = out_nodes + NODE_OUT;        // [640000,128]

  hipMemsetAsync(out_nodes, 0, NODE_OUT * sizeof(float), stream);
  transpose_weights<<<448, 256, 0, stream>>>(eW1, eW2, nW1, nW2, wt);

  const bool use_xb = ws_size >= (size_t)WS_NEED_BYTES;
  bf16* xb = wt + XB_OFF;
  if (use_xb) {
    convert_x<<<625, 256, 0, stream>>>(x, xb);
    edge_mlp<true><<<512, 256, 0, stream>>>(x, xb, eidx, ea, eb1, eb2, wt, out_edges);
    node_mlp<true><<<512, 256, 0, stream>>>(x, xb, eidx, out_edges, nb1, nb2, wt, out_nodes);
  } else {
    edge_mlp<false><<<512, 256, 0, stream>>>(x, nullptr, eidx, ea, eb1, eb2, wt, out_edges);
    node_mlp<false><<<512, 256, 0, stream>>>(x, nullptr, eidx, out_edges, nb1, nb2, wt, out_nodes);
  }
}

// Round 8
// 834.279 us; speedup vs baseline: 2.1705x; 1.0059x over previous
//
#include <hip/hip_runtime.h>
#include <cstdint>

#define N_NODES   10000
#define N_EDGES   640000
#define NODE_OUT  (N_NODES * 128)       // 1,280,000 node-output floats

typedef __bf16 bf16;
typedef bf16  bf16x8 __attribute__((ext_vector_type(8)));
typedef float f32x4  __attribute__((ext_vector_type(4)));

// ws layout (bytes):
//   wt (bf16 weights, transposed)            229,376
//   xb (bf16 copy of x)                    2,560,000
//   cur (int[10016] hist/offsets)             40,064
//   perm (int[640000])                     2,560,000
//   csort (int[640000])                    2,560,000
#define EW1T_OFF 0        // bf16-elem offsets inside wt
#define EW2T_OFF 49152
#define NW1T_OFF 65536
#define NW2T_OFF 98304
#define XB_OFF   114688
#define WS_XB_BYTES    (229376 + 2560000)
#define CUR_BYTE_OFF   WS_XB_BYTES
#define PERM_BYTE_OFF  (CUR_BYTE_OFF + 40064)
#define CSORT_BYTE_OFF (PERM_BYTE_OFF + 2560000)
#define WS_SORT_BYTES  (CSORT_BYTE_OFF + 2560000)

// -------- weight convert+transpose: fp32 W[K][N] -> bf16 WT[N][K] --------
__global__ void transpose_weights(const float* __restrict__ eW1, const float* __restrict__ eW2,
                                  const float* __restrict__ nW1, const float* __restrict__ nW2,
                                  bf16* __restrict__ wt) {
  int gid = blockIdx.x * 256 + threadIdx.x;   // 448*256 = 114688 exactly
  const float* src; bf16* dst; int K, off;
  if (gid < 49152)      { src = eW1; dst = wt + EW1T_OFF; K = 384; off = gid; }
  else if (gid < 65536) { src = eW2; dst = wt + EW2T_OFF; K = 128; off = gid - 49152; }
  else if (gid < 98304) { src = nW1; dst = wt + NW1T_OFF; K = 256; off = gid - 65536; }
  else                  { src = nW2; dst = wt + NW2T_OFF; K = 128; off = gid - 98304; }
  int k = off >> 7, n = off & 127;
  dst[n * K + k] = (bf16)src[off];
}

__device__ __forceinline__ float softplus_f(float v) {
  return v > 20.f ? v : __logf(1.f + __expf(v));
}

__device__ __forceinline__ bf16x8 cvt8(float4 f0, float4 f1) {
  bf16x8 h;
  h[0] = (bf16)f0.x; h[1] = (bf16)f0.y; h[2] = (bf16)f0.z; h[3] = (bf16)f0.w;
  h[4] = (bf16)f1.x; h[5] = (bf16)f1.y; h[6] = (bf16)f1.z; h[7] = (bf16)f1.w;
  return h;
}

__device__ __forceinline__ bf16x8 load_cvt8(const float* __restrict__ src) {
  float4 f0 = *(const float4*)src;
  float4 f1 = *(const float4*)(src + 4);
  return cvt8(f0, f1);
}

// one-time x -> bf16 copy (gathered ~128x each; bf16 halves gather bytes)
__global__ void convert_x(const float* __restrict__ x, bf16* __restrict__ xb) {
  int i = (blockIdx.x * 256 + threadIdx.x) * 8;   // 625*256*8 = 1,280,000 exactly
  *(bf16x8*)&xb[i] = load_cvt8(x + i);
}

// -------- counting sort of edges by destination (col) --------
__global__ void hist_k(const int* __restrict__ eidx, int* __restrict__ hist) {
  int g = blockIdx.x * 256 + threadIdx.x;          // 2500*256 = 640000
  atomicAdd(&hist[eidx[N_EDGES + g]], 1);
}

__global__ void scan_k(int* __restrict__ cur) {    // 1 block, 1024 thr, in-place
  __shared__ int part[1024];
  int tid = threadIdx.x;
  int base = tid * 10;
  int loc[10]; int s = 0;
  #pragma unroll
  for (int i = 0; i < 10; ++i) {
    int v = (base + i < N_NODES) ? cur[base + i] : 0;
    loc[i] = s; s += v;
  }
  part[tid] = s; __syncthreads();
  for (int off = 1; off < 1024; off <<= 1) {
    int v = (tid >= off) ? part[tid - off] : 0;
    __syncthreads(); part[tid] += v; __syncthreads();
  }
  int pre = tid ? part[tid - 1] : 0;
  #pragma unroll
  for (int i = 0; i < 10; ++i)
    if (base + i < N_NODES) cur[base + i] = pre + loc[i];
}

__global__ void scatter_k(const int* __restrict__ eidx, int* __restrict__ cur,
                          int* __restrict__ perm, int* __restrict__ csort) {
  int g = blockIdx.x * 256 + threadIdx.x;
  int c = eidx[N_EDGES + g];
  int p = atomicAdd(&cur[c], 1);
  perm[p] = g; csort[p] = c;
}

// ============ edge MLP: GEMM1(K=384)+softplus, GEMM2(K=128) ============
// (unchanged from R7: 4 waves, 32-col strips, reg weights, T14 pipelined staging)
template<bool XB>
__global__ void __launch_bounds__(256, 2)
edge_mlp(const float* __restrict__ x, const bf16* __restrict__ xb,
         const int* __restrict__ eidx, const float* __restrict__ edge_attr,
         const float* __restrict__ eb1, const float* __restrict__ eb2,
         const bf16* __restrict__ wt, float* __restrict__ edge_out)
{
  __shared__ bf16 sA[32 * 384];   // 24,576 B : slots 0-15 x_row | 16-31 x_col | 32-47 ea
  __shared__ bf16 sC[32 * 128];   //  8,192 B : C1, swizzled

  const int tid  = threadIdx.x;
  const int wave = tid >> 6, lane = tid & 63;
  const int ln15 = lane & 15, lq = lane >> 4;
  const int n0 = wave * 32;
  const int sw = ln15 & 7;

  bf16x8 w1[12][2], w2[4][2];
  #pragma unroll
  for (int c = 0; c < 12; ++c)
    #pragma unroll
    for (int t = 0; t < 2; ++t)
      w1[c][t] = *(const bf16x8*)&wt[EW1T_OFF + (n0 + t * 16 + ln15) * 384 + c * 32 + lq * 8];
  #pragma unroll
  for (int c = 0; c < 4; ++c)
    #pragma unroll
    for (int t = 0; t < 2; ++t)
      w2[c][t] = *(const bf16x8*)&wt[EW2T_OFF + (n0 + t * 16 + ln15) * 128 + c * 32 + lq * 8];
  float b1[2], b2[2];
  #pragma unroll
  for (int t = 0; t < 2; ++t) {
    b1[t] = eb1[n0 + t * 16 + ln15];
    b2[t] = eb2[n0 + t * 16 + ln15];
  }

  const int eA = tid >> 4, eB = eA + 16;
  const int pl = tid & 15, lp = pl ^ (eA & 7);

  uint4  hx0, hx1, hc0, hc1;
  float4 px0[2], px1[2], pc0[2], pc1[2];
  float4 pa0[2], pa1[2];

  const int NT = N_EDGES / 32;

  {
    const int e0 = blockIdx.x * 32;
    int riA = eidx[e0 + eA], riB = eidx[e0 + eB];
    int ciA = eidx[N_EDGES + e0 + eA], ciB = eidx[N_EDGES + e0 + eB];
    if constexpr (XB) {
      hx0 = *(const uint4*)&xb[(size_t)riA * 128 + lp * 8];
      hx1 = *(const uint4*)&xb[(size_t)riB * 128 + lp * 8];
      hc0 = *(const uint4*)&xb[(size_t)ciA * 128 + lp * 8];
      hc1 = *(const uint4*)&xb[(size_t)ciB * 128 + lp * 8];
    } else {
      px0[0] = *(const float4*)(x + (size_t)riA * 128 + lp * 8);
      px0[1] = *(const float4*)(x + (size_t)riA * 128 + lp * 8 + 4);
      px1[0] = *(const float4*)(x + (size_t)riB * 128 + lp * 8);
      px1[1] = *(const float4*)(x + (size_t)riB * 128 + lp * 8 + 4);
      pc0[0] = *(const float4*)(x + (size_t)ciA * 128 + lp * 8);
      pc0[1] = *(const float4*)(x + (size_t)ciA * 128 + lp * 8 + 4);
      pc1[0] = *(const float4*)(x + (size_t)ciB * 128 + lp * 8);
      pc1[1] = *(const float4*)(x + (size_t)ciB * 128 + lp * 8 + 4);
    }
    pa0[0] = *(const float4*)(edge_attr + (size_t)(e0 + eA) * 128 + lp * 8);
    pa0[1] = *(const float4*)(edge_attr + (size_t)(e0 + eA) * 128 + lp * 8 + 4);
    pa1[0] = *(const float4*)(edge_attr + (size_t)(e0 + eB) * 128 + lp * 8);
    pa1[1] = *(const float4*)(edge_attr + (size_t)(e0 + eB) * 128 + lp * 8 + 4);
  }

  for (int tile = blockIdx.x; tile < NT; tile += gridDim.x) {
    const int e0 = tile * 32;

    if constexpr (XB) {
      *(uint4*)&sA[eA * 384 + (0 * 16 + pl) * 8] = hx0;
      *(uint4*)&sA[eB * 384 + (0 * 16 + pl) * 8] = hx1;
      *(uint4*)&sA[eA * 384 + (1 * 16 + pl) * 8] = hc0;
      *(uint4*)&sA[eB * 384 + (1 * 16 + pl) * 8] = hc1;
    } else {
      *(bf16x8*)&sA[eA * 384 + (0 * 16 + pl) * 8] = cvt8(px0[0], px0[1]);
      *(bf16x8*)&sA[eB * 384 + (0 * 16 + pl) * 8] = cvt8(px1[0], px1[1]);
      *(bf16x8*)&sA[eA * 384 + (1 * 16 + pl) * 8] = cvt8(pc0[0], pc0[1]);
      *(bf16x8*)&sA[eB * 384 + (1 * 16 + pl) * 8] = cvt8(pc1[0], pc1[1]);
    }
    *(bf16x8*)&sA[eA * 384 + (2 * 16 + pl) * 8] = cvt8(pa0[0], pa0[1]);
    *(bf16x8*)&sA[eB * 384 + (2 * 16 + pl) * 8] = cvt8(pa1[0], pa1[1]);

    const int tn = tile + gridDim.x;
    if (tn < NT) {
      const int en = tn * 32;
      int riA = eidx[en + eA], riB = eidx[en + eB];
      int ciA = eidx[N_EDGES + en + eA], ciB = eidx[N_EDGES + en + eB];
      if constexpr (XB) {
        hx0 = *(const uint4*)&xb[(size_t)riA * 128 + lp * 8];
        hx1 = *(const uint4*)&xb[(size_t)riB * 128 + lp * 8];
        hc0 = *(const uint4*)&xb[(size_t)ciA * 128 + lp * 8];
        hc1 = *(const uint4*)&xb[(size_t)ciB * 128 + lp * 8];
      } else {
        px0[0] = *(const float4*)(x + (size_t)riA * 128 + lp * 8);
        px0[1] = *(const float4*)(x + (size_t)riA * 128 + lp * 8 + 4);
        px1[0] = *(const float4*)(x + (size_t)riB * 128 + lp * 8);
        px1[1] = *(const float4*)(x + (size_t)riB * 128 + lp * 8 + 4);
        pc0[0] = *(const float4*)(x + (size_t)ciA * 128 + lp * 8);
        pc0[1] = *(const float4*)(x + (size_t)ciA * 128 + lp * 8 + 4);
        pc1[0] = *(const float4*)(x + (size_t)ciB * 128 + lp * 8);
        pc1[1] = *(const float4*)(x + (size_t)ciB * 128 + lp * 8 + 4);
      }
      pa0[0] = *(const float4*)(edge_attr + (size_t)(en + eA) * 128 + lp * 8);
      pa0[1] = *(const float4*)(edge_attr + (size_t)(en + eA) * 128 + lp * 8 + 4);
      pa1[0] = *(const float4*)(edge_attr + (size_t)(en + eB) * 128 + lp * 8);
      pa1[1] = *(const float4*)(edge_attr + (size_t)(en + eB) * 128 + lp * 8 + 4);
    }
    __syncthreads();   // S1

    f32x4 acc[2][2];
    #pragma unroll
    for (int mf = 0; mf < 2; ++mf)
      #pragma unroll
      for (int t = 0; t < 2; ++t)
        acc[mf][t] = f32x4{0.f, 0.f, 0.f, 0.f};
    #pragma unroll
    for (int c = 0; c < 12; ++c) {
      int s = (((c * 4 + lq) ^ sw) << 3);
      bf16x8 a0 = *(const bf16x8*)&sA[ln15 * 384 + s];
      bf16x8 a1 = *(const bf16x8*)&sA[(16 + ln15) * 384 + s];
      #pragma unroll
      for (int t = 0; t < 2; ++t) {
        acc[0][t] = __builtin_amdgcn_mfma_f32_16x16x32_bf16(a0, w1[c][t], acc[0][t], 0, 0, 0);
        acc[1][t] = __builtin_amdgcn_mfma_f32_16x16x32_bf16(a1, w1[c][t], acc[1][t], 0, 0, 0);
      }
    }

    #pragma unroll
    for (int mf = 0; mf < 2; ++mf)
      #pragma unroll
      for (int t = 0; t < 2; ++t)
        #pragma unroll
        for (int r = 0; r < 4; ++r) {
          float v = softplus_f(acc[mf][t][r] + b1[t]);
          int row = mf * 16 + lq * 4 + r;
          int col = n0 + t * 16 + ln15;
          sC[row * 128 + ((((col >> 3) ^ (row & 7))) << 3) + (col & 7)] = (bf16)v;
        }
    __syncthreads();   // S2

    f32x4 d[2][2];
    #pragma unroll
    for (int mf = 0; mf < 2; ++mf)
      #pragma unroll
      for (int t = 0; t < 2; ++t)
        d[mf][t] = f32x4{0.f, 0.f, 0.f, 0.f};
    #pragma unroll
    for (int c = 0; c < 4; ++c) {
      int s = (((c * 4 + lq) ^ sw) << 3);
      bf16x8 a0 = *(const bf16x8*)&sC[ln15 * 128 + s];
      bf16x8 a1 = *(const bf16x8*)&sC[(16 + ln15) * 128 + s];
      #pragma unroll
      for (int t = 0; t < 2; ++t) {
        d[0][t] = __builtin_amdgcn_mfma_f32_16x16x32_bf16(a0, w2[c][t], d[0][t], 0, 0, 0);
        d[1][t] = __builtin_amdgcn_mfma_f32_16x16x32_bf16(a1, w2[c][t], d[1][t], 0, 0, 0);
      }
    }
    #pragma unroll
    for (int mf = 0; mf < 2; ++mf)
      #pragma unroll
      for (int t = 0; t < 2; ++t)
        #pragma unroll
        for (int r = 0; r < 4; ++r) {
          int row = mf * 16 + lq * 4 + r;
          edge_out[(size_t)(e0 + row) * 128 + n0 + t * 16 + ln15] = d[mf][t][r] + b2[t];
        }
  }
}

// ============ node MLP: GEMM3(K=256)+softplus, GEMM4(K=128)+aggregated scatter ============
// SORTED: edges processed in col-sorted order via perm/csort; epilogue aggregates
// same-destination rows (wave-uniform 16-row fast path -> 1 atomic/16 rows).
template<bool XB, bool SORTED>
__global__ void __launch_bounds__(256, 2)
node_mlp(const float* __restrict__ x, const bf16* __restrict__ xb,
         const int* __restrict__ eidx, const float* __restrict__ edge_new,
         const int* __restrict__ perm, const int* __restrict__ csort,
         const float* __restrict__ nb1, const float* __restrict__ nb2,
         const bf16* __restrict__ wt, float* __restrict__ node_out)
{
  __shared__ bf16 sA[32 * 384];   // slots 0-15 x_row | 16-31 C2 | 32-47 C3

  const int tid  = threadIdx.x;
  const int wave = tid >> 6, lane = tid & 63;
  const int ln15 = lane & 15, lq = lane >> 4;
  const int n0 = wave * 32;
  const int sw = ln15 & 7;

  bf16x8 w3[8][2], w4[4][2];
  #pragma unroll
  for (int c = 0; c < 8; ++c)
    #pragma unroll
    for (int t = 0; t < 2; ++t)
      w3[c][t] = *(const bf16x8*)&wt[NW1T_OFF + (n0 + t * 16 + ln15) * 256 + c * 32 + lq * 8];
  #pragma unroll
  for (int c = 0; c < 4; ++c)
    #pragma unroll
    for (int t = 0; t < 2; ++t)
      w4[c][t] = *(const bf16x8*)&wt[NW2T_OFF + (n0 + t * 16 + ln15) * 128 + c * 32 + lq * 8];
  float b3[2], b4[2];
  #pragma unroll
  for (int t = 0; t < 2; ++t) {
    b3[t] = nb1[n0 + t * 16 + ln15];
    b4[t] = nb2[n0 + t * 16 + ln15];
  }

  const int eA = tid >> 4, eB = eA + 16;
  const int pl = tid & 15, lp = pl ^ (eA & 7);

  uint4  hx0, hx1;
  float4 px0[2], px1[2];
  float4 pe0[2], pe1[2];

  const int NT = N_EDGES / 32;

  {
    const int e0 = blockIdx.x * 32;
    int epA, epB;
    if constexpr (SORTED) { epA = perm[e0 + eA]; epB = perm[e0 + eB]; }
    else                  { epA = e0 + eA;       epB = e0 + eB; }
    int riA = eidx[epA], riB = eidx[epB];
    if constexpr (XB) {
      hx0 = *(const uint4*)&xb[(size_t)riA * 128 + lp * 8];
      hx1 = *(const uint4*)&xb[(size_t)riB * 128 + lp * 8];
    } else {
      px0[0] = *(const float4*)(x + (size_t)riA * 128 + lp * 8);
      px0[1] = *(const float4*)(x + (size_t)riA * 128 + lp * 8 + 4);
      px1[0] = *(const float4*)(x + (size_t)riB * 128 + lp * 8);
      px1[1] = *(const float4*)(x + (size_t)riB * 128 + lp * 8 + 4);
    }
    pe0[0] = *(const float4*)(edge_new + (size_t)epA * 128 + lp * 8);
    pe0[1] = *(const float4*)(edge_new + (size_t)epA * 128 + lp * 8 + 4);
    pe1[0] = *(const float4*)(edge_new + (size_t)epB * 128 + lp * 8);
    pe1[1] = *(const float4*)(edge_new + (size_t)epB * 128 + lp * 8 + 4);
  }

  for (int tile = blockIdx.x; tile < NT; tile += gridDim.x) {
    const int e0 = tile * 32;

    if constexpr (XB) {
      *(uint4*)&sA[eA * 384 + (0 * 16 + pl) * 8] = hx0;
      *(uint4*)&sA[eB * 384 + (0 * 16 + pl) * 8] = hx1;
    } else {
      *(bf16x8*)&sA[eA * 384 + (0 * 16 + pl) * 8] = cvt8(px0[0], px0[1]);
      *(bf16x8*)&sA[eB * 384 + (0 * 16 + pl) * 8] = cvt8(px1[0], px1[1]);
    }
    *(bf16x8*)&sA[eA * 384 + (1 * 16 + pl) * 8] = cvt8(pe0[0], pe0[1]);
    *(bf16x8*)&sA[eB * 384 + (1 * 16 + pl) * 8] = cvt8(pe1[0], pe1[1]);

    const int tn = tile + gridDim.x;
    if (tn < NT) {
      const int en = tn * 32;
      int epA, epB;
      if constexpr (SORTED) { epA = perm[en + eA]; epB = perm[en + eB]; }
      else                  { epA = en + eA;       epB = en + eB; }
      int riA = eidx[epA], riB = eidx[epB];
      if constexpr (XB) {
        hx0 = *(const uint4*)&xb[(size_t)riA * 128 + lp * 8];
        hx1 = *(const uint4*)&xb[(size_t)riB * 128 + lp * 8];
      } else {
        px0[0] = *(const float4*)(x + (size_t)riA * 128 + lp * 8);
        px0[1] = *(const float4*)(x + (size_t)riA * 128 + lp * 8 + 4);
        px1[0] = *(const float4*)(x + (size_t)riB * 128 + lp * 8);
        px1[1] = *(const float4*)(x + (size_t)riB * 128 + lp * 8 + 4);
      }
      pe0[0] = *(const float4*)(edge_new + (size_t)epA * 128 + lp * 8);
      pe0[1] = *(const float4*)(edge_new + (size_t)epA * 128 + lp * 8 + 4);
      pe1[0] = *(const float4*)(edge_new + (size_t)epB * 128 + lp * 8);
      pe1[1] = *(const float4*)(edge_new + (size_t)epB * 128 + lp * 8 + 4);
    }
    __syncthreads();   // S1

    f32x4 acc[2][2];
    #pragma unroll
    for (int mf = 0; mf < 2; ++mf)
      #pragma unroll
      for (int t = 0; t < 2; ++t)
        acc[mf][t] = f32x4{0.f, 0.f, 0.f, 0.f};
    #pragma unroll
    for (int c = 0; c < 8; ++c) {
      int s = (((c * 4 + lq) ^ sw) << 3);
      bf16x8 a0 = *(const bf16x8*)&sA[ln15 * 384 + s];
      bf16x8 a1 = *(const bf16x8*)&sA[(16 + ln15) * 384 + s];
      #pragma unroll
      for (int t = 0; t < 2; ++t) {
        acc[0][t] = __builtin_amdgcn_mfma_f32_16x16x32_bf16(a0, w3[c][t], acc[0][t], 0, 0, 0);
        acc[1][t] = __builtin_amdgcn_mfma_f32_16x16x32_bf16(a1, w3[c][t], acc[1][t], 0, 0, 0);
      }
    }

    #pragma unroll
    for (int mf = 0; mf < 2; ++mf)
      #pragma unroll
      for (int t = 0; t < 2; ++t)
        #pragma unroll
        for (int r = 0; r < 4; ++r) {
          float v = softplus_f(acc[mf][t][r] + b3[t]);
          int row = mf * 16 + lq * 4 + r;
          int col = n0 + t * 16 + ln15;
          int ls  = 32 + (col >> 3);
          sA[row * 384 + ((ls ^ (row & 7)) << 3) + (col & 7)] = (bf16)v;
        }
    __syncthreads();   // S2

    f32x4 d[2][2];
    #pragma unroll
    for (int mf = 0; mf < 2; ++mf)
      #pragma unroll
      for (int t = 0; t < 2; ++t)
        d[mf][t] = f32x4{0.f, 0.f, 0.f, 0.f};
    #pragma unroll
    for (int c = 0; c < 4; ++c) {
      int s = (((32 + c * 4 + lq) ^ sw) << 3);
      bf16x8 a0 = *(const bf16x8*)&sA[ln15 * 384 + s];
      bf16x8 a1 = *(const bf16x8*)&sA[(16 + ln15) * 384 + s];
      #pragma unroll
      for (int t = 0; t < 2; ++t) {
        d[0][t] = __builtin_amdgcn_mfma_f32_16x16x32_bf16(a0, w4[c][t], d[0][t], 0, 0, 0);
        d[1][t] = __builtin_amdgcn_mfma_f32_16x16x32_bf16(a1, w4[c][t], d[1][t], 0, 0, 0);
      }
    }

    if constexpr (SORTED) {
      #pragma unroll
      for (int mf = 0; mf < 2; ++mf) {
        int4 q = *(const int4*)&csort[e0 + mf * 16 + lq * 4];
        int nid[4] = {q.x, q.y, q.z, q.w};
        bool all4 = (nid[0] == nid[1]) && (nid[1] == nid[2]) && (nid[2] == nid[3]);
        int first0 = __shfl(nid[0], ln15);   // nid of row 0 (lane lq=0, same ln15)
        bool uni = __all(all4 && (nid[0] == first0));
        #pragma unroll
        for (int t = 0; t < 2; ++t) {
          int col = n0 + t * 16 + ln15;
          float v[4];
          #pragma unroll
          for (int r = 0; r < 4; ++r) v[r] = d[mf][t][r] + b4[t];
          if (uni) {
            float s = (v[0] + v[1]) + (v[2] + v[3]);
            s += __shfl_xor(s, 16);
            s += __shfl_xor(s, 32);
            if (lq == 0)
              unsafeAtomicAdd(&node_out[(size_t)nid[0] * 128 + col], s);
          } else {
            float s = v[0]; int curn = nid[0];
            #pragma unroll
            for (int r = 1; r < 4; ++r) {
              if (nid[r] == curn) s += v[r];
              else {
                unsafeAtomicAdd(&node_out[(size_t)curn * 128 + col], s);
                curn = nid[r]; s = v[r];
              }
            }
            unsafeAtomicAdd(&node_out[(size_t)curn * 128 + col], s);
          }
        }
      }
    } else {
      #pragma unroll
      for (int mf = 0; mf < 2; ++mf) {
        int4 q = *(const int4*)&eidx[N_EDGES + e0 + mf * 16 + lq * 4];
        int nid[4] = {q.x, q.y, q.z, q.w};
        #pragma unroll
        for (int t = 0; t < 2; ++t) {
          int col = n0 + t * 16 + ln15;
          #pragma unroll
          for (int r = 0; r < 4; ++r) {
            float v = d[mf][t][r] + b4[t];
            unsafeAtomicAdd(&node_out[(size_t)nid[r] * 128 + col], v);
          }
        }
      }
    }
  }
}

extern "C" void kernel_launch(void* const* d_in, const int* in_sizes, int n_in,
                              void* d_out, int out_size, void* d_ws, size_t ws_size,
                              hipStream_t stream) {
  const float* x    = (const float*)d_in[0];
  const int*   eidx = (const int*)d_in[1];
  const float* ea   = (const float*)d_in[2];
  const float* nW1  = (const float*)d_in[3];
  const float* nb1  = (const float*)d_in[4];
  const float* nW2  = (const float*)d_in[5];
  const float* nb2  = (const float*)d_in[6];
  const float* eW1  = (const float*)d_in[7];
  const float* eb1  = (const float*)d_in[8];
  const float* eW2  = (const float*)d_in[9];
  const float* eb2  = (const float*)d_in[10];

  bf16*  wt        = (bf16*)d_ws;
  float* out_nodes = (float*)d_out;               // [10000,128]
  float* out_edges = out_nodes + NODE_OUT;        // [640000,128]

  hipMemsetAsync(out_nodes, 0, NODE_OUT * sizeof(float), stream);
  transpose_weights<<<448, 256, 0, stream>>>(eW1, eW2, nW1, nW2, wt);

  const bool use_xb   = ws_size >= (size_t)WS_XB_BYTES;
  const bool use_sort = ws_size >= (size_t)WS_SORT_BYTES;   // implies use_xb
  bf16* xb   = wt + XB_OFF;
  int* cur   = (int*)((char*)d_ws + CUR_BYTE_OFF);
  int* perm  = (int*)((char*)d_ws + PERM_BYTE_OFF);
  int* csort = (int*)((char*)d_ws + CSORT_BYTE_OFF);

  if (use_sort) {
    convert_x<<<625, 256, 0, stream>>>(x, xb);
    hipMemsetAsync(cur, 0, N_NODES * sizeof(int), stream);
    hist_k<<<2500, 256, 0, stream>>>(eidx, cur);
    scan_k<<<1, 1024, 0, stream>>>(cur);
    scatter_k<<<2500, 256, 0, stream>>>(eidx, cur, perm, csort);
    edge_mlp<true><<<512, 256, 0, stream>>>(x, xb, eidx, ea, eb1, eb2, wt, out_edges);
    node_mlp<true, true><<<512, 256, 0, stream>>>(x, xb, eidx, out_edges, perm, csort,
                                                  nb1, nb2, wt, out_nodes);
  } else if (use_xb) {
    convert_x<<<625, 256, 0, stream>>>(x, xb);
    edge_mlp<true><<<512, 256, 0, stream>>>(x, xb, eidx, ea, eb1, eb2, wt, out_edges);
    node_mlp<true, false><<<512, 256, 0, stream>>>(x, xb, eidx, out_edges, nullptr, nullptr,
                                                   nb1, nb2, wt, out_nodes);
  } else {
    edge_mlp<false><<<512, 256, 0, stream>>>(x, nullptr, eidx, ea, eb1, eb2, wt, out_edges);
    node_mlp<false, false><<<512, 256, 0, stream>>>(x, nullptr, eidx, out_edges, nullptr, nullptr,
                                                    nb1, nb2, wt, out_nodes);
  }
}